// Round 1
// baseline (1225.892 us; speedup 1.0000x reference)
//
#include <hip/hip_runtime.h>
#include <hip/hip_bf16.h>

#define NN 8192
#define DD 512
#define HH 256
#define LL 64
#define EE 262144

typedef __attribute__((ext_vector_type(8))) short short8;
typedef __attribute__((ext_vector_type(4))) float f32x4;

// ---------------- zero accumulators ----------------
__global__ void k_zero(float* __restrict__ p, int n4) {
    int i = blockIdx.x * blockDim.x + threadIdx.x;
    if (i < n4) ((float4*)p)[i] = make_float4(0.f, 0.f, 0.f, 0.f);
}

// ---------------- GEMM1: xw1[N,H] = x[N,D] @ W1[D,H], f32 ----------------
// block: 256 threads, 16 rows x 256 cols tile; thread = 4 rows x 4 cols
__global__ __launch_bounds__(256) void k_gemm1(const float* __restrict__ x,
                                               const float* __restrict__ w1,
                                               float* __restrict__ xw1) {
    __shared__ float xs[16 * DD];  // 32 KB
    const int r0 = blockIdx.x * 16;
    const int tid = threadIdx.x;

    const float4* xsrc = (const float4*)(x + (size_t)r0 * DD);
    float4* xdst = (float4*)xs;
#pragma unroll
    for (int i = 0; i < 8; ++i) xdst[tid + i * 256] = xsrc[tid + i * 256];
    __syncthreads();

    const int ty = tid >> 6, tx = tid & 63;
    const int c0 = tx * 4;
    float acc[4][4] = {};

    for (int k = 0; k < DD; k += 4) {
        float4 xv[4];
#pragma unroll
        for (int rr = 0; rr < 4; ++rr)
            xv[rr] = *(const float4*)&xs[(ty * 4 + rr) * DD + k];
#pragma unroll
        for (int kk = 0; kk < 4; ++kk) {
            float4 w = *(const float4*)&w1[(size_t)(k + kk) * HH + c0];
#pragma unroll
            for (int rr = 0; rr < 4; ++rr) {
                float s = ((const float*)&xv[rr])[kk];
                acc[rr][0] = fmaf(s, w.x, acc[rr][0]);
                acc[rr][1] = fmaf(s, w.y, acc[rr][1]);
                acc[rr][2] = fmaf(s, w.z, acc[rr][2]);
                acc[rr][3] = fmaf(s, w.w, acc[rr][3]);
            }
        }
    }
#pragma unroll
    for (int rr = 0; rr < 4; ++rr) {
        int r = r0 + ty * 4 + rr;
        *(float4*)&xw1[(size_t)r * HH + c0] =
            make_float4(acc[rr][0], acc[rr][1], acc[rr][2], acc[rr][3]);
    }
}

// ---------------- SpMM1: hacc[row] += w * xw1[col], F=256 ----------------
// 64 threads per edge, 4 floats each (float4 load, 4 atomics)
__global__ __launch_bounds__(256) void k_spmm1(const int* __restrict__ erow,
                                               const int* __restrict__ ecol,
                                               const float* __restrict__ ew,
                                               const float* __restrict__ src,
                                               float* __restrict__ acc) {
    int t = blockIdx.x * 256 + threadIdx.x;
    int e = t >> 6;        // wave-uniform
    int lane = t & 63;
    if (e >= EE) return;
    int r = erow[e], c = ecol[e];
    float w = ew[e];
    float4 v = *(const float4*)&src[(size_t)c * HH + lane * 4];
    float* dst = &acc[(size_t)r * HH + lane * 4];
    atomicAdd(dst + 0, w * v.x);
    atomicAdd(dst + 1, w * v.y);
    atomicAdd(dst + 2, w * v.z);
    atomicAdd(dst + 3, w * v.w);
}

// ---------------- GEMM2: hw2[N,L] = relu(hacc)[N,H] @ W2[H,L] ----------------
__global__ __launch_bounds__(256) void k_gemm2(const float* __restrict__ hacc,
                                               const float* __restrict__ w2,
                                               float* __restrict__ hw2) {
    __shared__ float hs[16 * HH];  // 16 KB
    const int r0 = blockIdx.x * 16;
    const int tid = threadIdx.x;

    const float4* src = (const float4*)(hacc + (size_t)r0 * HH);
    float4* dst = (float4*)hs;
#pragma unroll
    for (int i = 0; i < 4; ++i) {
        float4 v = src[tid + i * 256];
        v.x = fmaxf(v.x, 0.f); v.y = fmaxf(v.y, 0.f);
        v.z = fmaxf(v.z, 0.f); v.w = fmaxf(v.w, 0.f);
        dst[tid + i * 256] = v;
    }
    __syncthreads();

    const int ty = tid >> 6, tx = tid & 63;  // tx = output col
    float acc[4] = {0.f, 0.f, 0.f, 0.f};

    for (int k = 0; k < HH; k += 4) {
        float4 hv[4];
#pragma unroll
        for (int rr = 0; rr < 4; ++rr)
            hv[rr] = *(const float4*)&hs[(ty * 4 + rr) * HH + k];
#pragma unroll
        for (int kk = 0; kk < 4; ++kk) {
            float w = w2[(size_t)(k + kk) * LL + tx];
#pragma unroll
            for (int rr = 0; rr < 4; ++rr)
                acc[rr] = fmaf(((const float*)&hv[rr])[kk], w, acc[rr]);
        }
    }
#pragma unroll
    for (int rr = 0; rr < 4; ++rr)
        hw2[(size_t)(r0 + ty * 4 + rr) * LL + tx] = acc[rr];
}

// ---------------- SpMM2: zacc[row] += w * hw2[col], F=64 ----------------
// 16 threads per edge, float4 each
__global__ __launch_bounds__(256) void k_spmm2(const int* __restrict__ erow,
                                               const int* __restrict__ ecol,
                                               const float* __restrict__ ew,
                                               const float* __restrict__ src,
                                               float* __restrict__ acc) {
    int t = blockIdx.x * 256 + threadIdx.x;
    int e = t >> 4;
    int lane = t & 15;
    if (e >= EE) return;
    int r = erow[e], c = ecol[e];
    float w = ew[e];
    float4 v = *(const float4*)&src[(size_t)c * LL + lane * 4];
    float* dst = &acc[(size_t)r * LL + lane * 4];
    atomicAdd(dst + 0, w * v.x);
    atomicAdd(dst + 1, w * v.y);
    atomicAdd(dst + 2, w * v.z);
    atomicAdd(dst + 3, w * v.w);
}

// ---------------- relu + cast z -> bf16 ----------------
__global__ void k_cast(const float* __restrict__ z, unsigned short* __restrict__ zb, int n4) {
    int i = blockIdx.x * 256 + threadIdx.x;
    if (i >= n4) return;
    float4 v = ((const float4*)z)[i];
    __hip_bfloat16 b0 = __float2bfloat16(fmaxf(v.x, 0.f));
    __hip_bfloat16 b1 = __float2bfloat16(fmaxf(v.y, 0.f));
    __hip_bfloat16 b2 = __float2bfloat16(fmaxf(v.z, 0.f));
    __hip_bfloat16 b3 = __float2bfloat16(fmaxf(v.w, 0.f));
    ushort4 o;
    o.x = *(unsigned short*)&b0;
    o.y = *(unsigned short*)&b1;
    o.z = *(unsigned short*)&b2;
    o.w = *(unsigned short*)&b3;
    ((ushort4*)zb)[i] = o;
}

// ---------------- decode: out = (sigmoid(z z^T) + F)*(1-2F), bf16 MFMA ----------------
// block = 256 threads = 4 waves (2x2), 64x64 output tile; wave = 32x32 via
// 2x2 of mfma_f32_16x16x32_bf16, K=64 in 2 steps.
__global__ __launch_bounds__(256) void k_decode(const unsigned short* __restrict__ zb,
                                                float* __restrict__ out) {
    const int tid = threadIdx.x;
    const int wave = tid >> 6, lane = tid & 63;
    const int bi = blockIdx.y, bj = blockIdx.x;
    const int wr = wave >> 1, wc = wave & 1;
    const int rA = bi * 64 + wr * 32;  // output rows
    const int rB = bj * 64 + wc * 32;  // output cols
    const int lm = lane & 15, lh = lane >> 4;

    short8 a[2][2], b[2][2];
#pragma unroll
    for (int m = 0; m < 2; ++m)
#pragma unroll
        for (int s = 0; s < 2; ++s) {
            a[m][s] = *(const short8*)&zb[(size_t)(rA + m * 16 + lm) * LL + s * 32 + lh * 8];
            b[m][s] = *(const short8*)&zb[(size_t)(rB + m * 16 + lm) * LL + s * 32 + lh * 8];
        }

    f32x4 acc[2][2];
#pragma unroll
    for (int m = 0; m < 2; ++m)
#pragma unroll
        for (int n = 0; n < 2; ++n)
            acc[m][n] = (f32x4){0.f, 0.f, 0.f, 0.f};

#pragma unroll
    for (int m = 0; m < 2; ++m)
#pragma unroll
        for (int n = 0; n < 2; ++n)
#pragma unroll
            for (int s = 0; s < 2; ++s)
                acc[m][n] = __builtin_amdgcn_mfma_f32_16x16x32_bf16(
                    a[m][s], b[n][s], acc[m][n], 0, 0, 0);

    const float SCALE = 1.0f - 2.0f * 1e-7f;
    const float BIAS = 1e-7f * SCALE;
#pragma unroll
    for (int m = 0; m < 2; ++m)
#pragma unroll
        for (int n = 0; n < 2; ++n)
#pragma unroll
            for (int q = 0; q < 4; ++q) {
                float xv = acc[m][n][q];
                float sig = 1.0f / (1.0f + __expf(-xv));
                float val = fmaf(sig, SCALE, BIAS);
                size_t row = rA + m * 16 + lh * 4 + q;
                size_t col = rB + n * 16 + lm;
                out[row * NN + col] = val;
            }
}

// ---------------- launch ----------------
extern "C" void kernel_launch(void* const* d_in, const int* in_sizes, int n_in,
                              void* d_out, int out_size, void* d_ws, size_t ws_size,
                              hipStream_t stream) {
    const float* x    = (const float*)d_in[0];
    const int*   erow = (const int*)d_in[1];
    const int*   ecol = (const int*)d_in[2];
    const float* ew   = (const float*)d_in[3];
    const float* w1   = (const float*)d_in[4];
    const float* w2   = (const float*)d_in[5];
    float* out = (float*)d_out;

    float* ws   = (float*)d_ws;
    float* hacc = ws;                        // N*H
    float* zacc = hacc + (size_t)NN * HH;    // N*L
    float* xw1  = zacc + (size_t)NN * LL;    // N*H
    float* hw2  = xw1 + (size_t)NN * HH;     // N*L
    unsigned short* zb = (unsigned short*)(hw2 + (size_t)NN * LL);  // N*L bf16

    // zero the two accumulators (hacc, zacc are contiguous)
    int n4 = (NN * HH + NN * LL) / 4;
    k_zero<<<(n4 + 255) / 256, 256, 0, stream>>>(ws, n4);

    k_gemm1<<<NN / 16, 256, 0, stream>>>(x, w1, xw1);
    k_spmm1<<<EE * 64 / 256, 256, 0, stream>>>(erow, ecol, ew, xw1, hacc);
    k_gemm2<<<NN / 16, 256, 0, stream>>>(hacc, w2, hw2);
    k_spmm2<<<EE * 16 / 256, 256, 0, stream>>>(erow, ecol, ew, hw2, zacc);
    k_cast<<<(NN * LL / 4 + 255) / 256, 256, 0, stream>>>(zacc, zb, NN * LL / 4);
    k_decode<<<dim3(128, 128), 256, 0, stream>>>(zb, out);
}

// Round 2
// 180.098 us; speedup vs baseline: 6.8068x; 6.8068x over previous
//
#include <hip/hip_runtime.h>
#include <hip/hip_bf16.h>

#define NN 8192
#define DD 512
#define HH 256
#define LL 64
#define EE 262144
#define CAP 96

typedef __attribute__((ext_vector_type(8))) short short8;
typedef __attribute__((ext_vector_type(4))) float f32x4;

// ---------------- zero row counters ----------------
__global__ void k_zero_cnt(int* __restrict__ cnt) {
    int i = blockIdx.x * blockDim.x + threadIdx.x;
    if (i < NN) cnt[i] = 0;
}

// ---------------- bucket edges by row ----------------
__global__ __launch_bounds__(256) void k_bucket(const int* __restrict__ erow,
                                                const int* __restrict__ ecol,
                                                const float* __restrict__ ew,
                                                int* __restrict__ cnt,
                                                int* __restrict__ slotc,
                                                float* __restrict__ slotw) {
    int e = blockIdx.x * 256 + threadIdx.x;
    if (e >= EE) return;
    int r = erow[e];
    int pos = atomicAdd(&cnt[r], 1);
    if (pos < CAP) {
        slotc[r * CAP + pos] = ecol[e];
        slotw[r * CAP + pos] = ew[e];
    }
}

// ---------------- GEMM1: xw1[N,H] = x[N,D] @ W1[D,H], f32 ----------------
__global__ __launch_bounds__(256) void k_gemm1(const float* __restrict__ x,
                                               const float* __restrict__ w1,
                                               float* __restrict__ xw1) {
    __shared__ float xs[16 * DD];  // 32 KB
    const int r0 = blockIdx.x * 16;
    const int tid = threadIdx.x;

    const float4* xsrc = (const float4*)(x + (size_t)r0 * DD);
    float4* xdst = (float4*)xs;
#pragma unroll
    for (int i = 0; i < 8; ++i) xdst[tid + i * 256] = xsrc[tid + i * 256];
    __syncthreads();

    const int ty = tid >> 6, tx = tid & 63;
    const int c0 = tx * 4;
    float acc[4][4] = {};

    for (int k = 0; k < DD; k += 4) {
        float4 xv[4];
#pragma unroll
        for (int rr = 0; rr < 4; ++rr)
            xv[rr] = *(const float4*)&xs[(ty * 4 + rr) * DD + k];
#pragma unroll
        for (int kk = 0; kk < 4; ++kk) {
            float4 w = *(const float4*)&w1[(size_t)(k + kk) * HH + c0];
#pragma unroll
            for (int rr = 0; rr < 4; ++rr) {
                float s = ((const float*)&xv[rr])[kk];
                acc[rr][0] = fmaf(s, w.x, acc[rr][0]);
                acc[rr][1] = fmaf(s, w.y, acc[rr][1]);
                acc[rr][2] = fmaf(s, w.z, acc[rr][2]);
                acc[rr][3] = fmaf(s, w.w, acc[rr][3]);
            }
        }
    }
#pragma unroll
    for (int rr = 0; rr < 4; ++rr) {
        int r = r0 + ty * 4 + rr;
        *(float4*)&xw1[(size_t)r * HH + c0] =
            make_float4(acc[rr][0], acc[rr][1], acc[rr][2], acc[rr][3]);
    }
}

// ---------------- SpMM1 (bucketed): hacc[row] = relu(sum w * xw1[col]) ----------------
// one wave per row; lane owns 4 of 256 features (float4); 4-edge unroll
__global__ __launch_bounds__(256) void k_spmm1_csr(const int* __restrict__ cnt,
                                                   const int* __restrict__ slotc,
                                                   const float* __restrict__ slotw,
                                                   const float* __restrict__ src,
                                                   float* __restrict__ dst) {
    const int tid = threadIdx.x;
    const int row = blockIdx.x * 4 + (tid >> 6);
    const int lane = tid & 63;
    const int deg = min(cnt[row], CAP);
    const int base = row * CAP;

    f32x4 acc = {0.f, 0.f, 0.f, 0.f};
    int i = 0;
    for (; i + 3 < deg; i += 4) {
        int4 c4 = *(const int4*)&slotc[base + i];
        float4 w4 = *(const float4*)&slotw[base + i];
        float4 v0 = *(const float4*)&src[(size_t)c4.x * HH + lane * 4];
        float4 v1 = *(const float4*)&src[(size_t)c4.y * HH + lane * 4];
        float4 v2 = *(const float4*)&src[(size_t)c4.z * HH + lane * 4];
        float4 v3 = *(const float4*)&src[(size_t)c4.w * HH + lane * 4];
        acc[0] = fmaf(w4.x, v0.x, acc[0]); acc[1] = fmaf(w4.x, v0.y, acc[1]);
        acc[2] = fmaf(w4.x, v0.z, acc[2]); acc[3] = fmaf(w4.x, v0.w, acc[3]);
        acc[0] = fmaf(w4.y, v1.x, acc[0]); acc[1] = fmaf(w4.y, v1.y, acc[1]);
        acc[2] = fmaf(w4.y, v1.z, acc[2]); acc[3] = fmaf(w4.y, v1.w, acc[3]);
        acc[0] = fmaf(w4.z, v2.x, acc[0]); acc[1] = fmaf(w4.z, v2.y, acc[1]);
        acc[2] = fmaf(w4.z, v2.z, acc[2]); acc[3] = fmaf(w4.z, v2.w, acc[3]);
        acc[0] = fmaf(w4.w, v3.x, acc[0]); acc[1] = fmaf(w4.w, v3.y, acc[1]);
        acc[2] = fmaf(w4.w, v3.z, acc[2]); acc[3] = fmaf(w4.w, v3.w, acc[3]);
    }
    for (; i < deg; ++i) {
        int c = slotc[base + i];
        float w = slotw[base + i];
        float4 v = *(const float4*)&src[(size_t)c * HH + lane * 4];
        acc[0] = fmaf(w, v.x, acc[0]); acc[1] = fmaf(w, v.y, acc[1]);
        acc[2] = fmaf(w, v.z, acc[2]); acc[3] = fmaf(w, v.w, acc[3]);
    }
    float4 o;
    o.x = fmaxf(acc[0], 0.f); o.y = fmaxf(acc[1], 0.f);
    o.z = fmaxf(acc[2], 0.f); o.w = fmaxf(acc[3], 0.f);
    *(float4*)&dst[(size_t)row * HH + lane * 4] = o;
}

// ---------------- GEMM2: hw2[N,L] = hacc[N,H] @ W2[H,L] (hacc pre-relu'd) ----------------
__global__ __launch_bounds__(256) void k_gemm2(const float* __restrict__ hacc,
                                               const float* __restrict__ w2,
                                               float* __restrict__ hw2) {
    __shared__ float hs[16 * HH];  // 16 KB
    const int r0 = blockIdx.x * 16;
    const int tid = threadIdx.x;

    const float4* src = (const float4*)(hacc + (size_t)r0 * HH);
    float4* dst = (float4*)hs;
#pragma unroll
    for (int i = 0; i < 4; ++i) dst[tid + i * 256] = src[tid + i * 256];
    __syncthreads();

    const int ty = tid >> 6, tx = tid & 63;  // tx = output col
    float acc[4] = {0.f, 0.f, 0.f, 0.f};

    for (int k = 0; k < HH; k += 4) {
        float4 hv[4];
#pragma unroll
        for (int rr = 0; rr < 4; ++rr)
            hv[rr] = *(const float4*)&hs[(ty * 4 + rr) * HH + k];
#pragma unroll
        for (int kk = 0; kk < 4; ++kk) {
            float w = w2[(size_t)(k + kk) * LL + tx];
#pragma unroll
            for (int rr = 0; rr < 4; ++rr)
                acc[rr] = fmaf(((const float*)&hv[rr])[kk], w, acc[rr]);
        }
    }
#pragma unroll
    for (int rr = 0; rr < 4; ++rr)
        hw2[(size_t)(r0 + ty * 4 + rr) * LL + tx] = acc[rr];
}

// ---------------- SpMM2 (bucketed): zb[row] = bf16(relu(sum w * hw2[col])) ----------------
// one wave per row; lane owns 1 of 64 features
__global__ __launch_bounds__(256) void k_spmm2_csr(const int* __restrict__ cnt,
                                                   const int* __restrict__ slotc,
                                                   const float* __restrict__ slotw,
                                                   const float* __restrict__ src,
                                                   unsigned short* __restrict__ zb) {
    const int tid = threadIdx.x;
    const int row = blockIdx.x * 4 + (tid >> 6);
    const int lane = tid & 63;
    const int deg = min(cnt[row], CAP);
    const int base = row * CAP;

    float acc = 0.f;
    int i = 0;
    for (; i + 3 < deg; i += 4) {
        int4 c4 = *(const int4*)&slotc[base + i];
        float4 w4 = *(const float4*)&slotw[base + i];
        float v0 = src[(size_t)c4.x * LL + lane];
        float v1 = src[(size_t)c4.y * LL + lane];
        float v2 = src[(size_t)c4.z * LL + lane];
        float v3 = src[(size_t)c4.w * LL + lane];
        acc = fmaf(w4.x, v0, acc);
        acc = fmaf(w4.y, v1, acc);
        acc = fmaf(w4.z, v2, acc);
        acc = fmaf(w4.w, v3, acc);
    }
    for (; i < deg; ++i) {
        int c = slotc[base + i];
        float w = slotw[base + i];
        acc = fmaf(w, src[(size_t)c * LL + lane], acc);
    }
    __hip_bfloat16 b = __float2bfloat16(fmaxf(acc, 0.f));
    zb[(size_t)row * LL + lane] = *(unsigned short*)&b;
}

// ---------------- decode: out = (sigmoid(z z^T) + F)*(1-2F), bf16 MFMA ----------------
__global__ __launch_bounds__(256) void k_decode(const unsigned short* __restrict__ zb,
                                                float* __restrict__ out) {
    const int tid = threadIdx.x;
    const int wave = tid >> 6, lane = tid & 63;
    const int bi = blockIdx.y, bj = blockIdx.x;
    const int wr = wave >> 1, wc = wave & 1;
    const int rA = bi * 64 + wr * 32;  // output rows
    const int rB = bj * 64 + wc * 32;  // output cols
    const int lm = lane & 15, lh = lane >> 4;

    short8 a[2][2], b[2][2];
#pragma unroll
    for (int m = 0; m < 2; ++m)
#pragma unroll
        for (int s = 0; s < 2; ++s) {
            a[m][s] = *(const short8*)&zb[(size_t)(rA + m * 16 + lm) * LL + s * 32 + lh * 8];
            b[m][s] = *(const short8*)&zb[(size_t)(rB + m * 16 + lm) * LL + s * 32 + lh * 8];
        }

    f32x4 acc[2][2];
#pragma unroll
    for (int m = 0; m < 2; ++m)
#pragma unroll
        for (int n = 0; n < 2; ++n)
            acc[m][n] = (f32x4){0.f, 0.f, 0.f, 0.f};

#pragma unroll
    for (int m = 0; m < 2; ++m)
#pragma unroll
        for (int n = 0; n < 2; ++n)
#pragma unroll
            for (int s = 0; s < 2; ++s)
                acc[m][n] = __builtin_amdgcn_mfma_f32_16x16x32_bf16(
                    a[m][s], b[n][s], acc[m][n], 0, 0, 0);

    const float SCALE = 1.0f - 2.0f * 1e-7f;
    const float BIAS = 1e-7f * SCALE;
#pragma unroll
    for (int m = 0; m < 2; ++m)
#pragma unroll
        for (int n = 0; n < 2; ++n)
#pragma unroll
            for (int q = 0; q < 4; ++q) {
                float xv = acc[m][n][q];
                float sig = 1.0f / (1.0f + __expf(-xv));
                float val = fmaf(sig, SCALE, BIAS);
                size_t row = rA + m * 16 + lh * 4 + q;
                size_t col = rB + n * 16 + lm;
                out[row * NN + col] = val;
            }
}

// ---------------- launch ----------------
extern "C" void kernel_launch(void* const* d_in, const int* in_sizes, int n_in,
                              void* d_out, int out_size, void* d_ws, size_t ws_size,
                              hipStream_t stream) {
    const float* x    = (const float*)d_in[0];
    const int*   erow = (const int*)d_in[1];
    const int*   ecol = (const int*)d_in[2];
    const float* ew   = (const float*)d_in[3];
    const float* w1   = (const float*)d_in[4];
    const float* w2   = (const float*)d_in[5];
    float* out = (float*)d_out;

    char* p = (char*)d_ws;
    float* xw1  = (float*)p;             p += (size_t)NN * HH * 4;   // 8 MB
    float* hacc = (float*)p;             p += (size_t)NN * HH * 4;   // 8 MB
    float* hw2  = (float*)p;             p += (size_t)NN * LL * 4;   // 2 MB
    unsigned short* zb = (unsigned short*)p; p += (size_t)NN * LL * 2; // 1 MB
    int*   cnt  = (int*)p;               p += (size_t)NN * 4;        // 32 KB
    int*   slotc = (int*)p;              p += (size_t)NN * CAP * 4;  // 3 MB
    float* slotw = (float*)p;            p += (size_t)NN * CAP * 4;  // 3 MB

    k_zero_cnt<<<NN / 256, 256, 0, stream>>>(cnt);
    k_bucket<<<EE / 256, 256, 0, stream>>>(erow, ecol, ew, cnt, slotc, slotw);
    k_gemm1<<<NN / 16, 256, 0, stream>>>(x, w1, xw1);
    k_spmm1_csr<<<NN / 4, 256, 0, stream>>>(cnt, slotc, slotw, xw1, hacc);
    k_gemm2<<<NN / 16, 256, 0, stream>>>(hacc, w2, hw2);
    k_spmm2_csr<<<NN / 4, 256, 0, stream>>>(cnt, slotc, slotw, hw2, zb);
    k_decode<<<dim3(128, 128), 256, 0, stream>>>(zb, out);
}

// Round 3
// 166.915 us; speedup vs baseline: 7.3444x; 1.0790x over previous
//
#include <hip/hip_runtime.h>
#include <hip/hip_bf16.h>

#define NN 8192
#define DD 512
#define HH 256
#define LL 64
#define EE 262144
#define CAP 96

typedef __attribute__((ext_vector_type(8))) short short8;
typedef __attribute__((ext_vector_type(4))) float f32x4;

__device__ __forceinline__ unsigned short f2b(float f) {
    __hip_bfloat16 b = __float2bfloat16(f);
    return *(unsigned short*)&b;
}
__device__ __forceinline__ float b2f(unsigned short u) {
    unsigned int x = ((unsigned int)u) << 16;
    union { unsigned int i; float f; } c; c.i = x; return c.f;
}

// ---------------- zero row counters ----------------
__global__ void k_zero_cnt(int* __restrict__ cnt) {
    int i = blockIdx.x * blockDim.x + threadIdx.x;
    if (i < NN) cnt[i] = 0;
}

// ---------------- bucket edges by row ----------------
__global__ __launch_bounds__(256) void k_bucket(const int* __restrict__ erow,
                                                const int* __restrict__ ecol,
                                                const float* __restrict__ ew,
                                                int* __restrict__ cnt,
                                                int* __restrict__ slotc,
                                                float* __restrict__ slotw) {
    int e = blockIdx.x * 256 + threadIdx.x;
    if (e >= EE) return;
    int r = erow[e];
    int pos = atomicAdd(&cnt[r], 1);
    if (pos < CAP) {
        slotc[r * CAP + pos] = ecol[e];
        slotw[r * CAP + pos] = ew[e];
    }
}

// ---------------- cast x -> bf16 ----------------
__global__ void k_cast_x(const float* __restrict__ x, unsigned short* __restrict__ xb, int n4) {
    int i = blockIdx.x * 256 + threadIdx.x;
    if (i >= n4) return;
    float4 v = ((const float4*)x)[i];
    ushort4 o;
    o.x = f2b(v.x); o.y = f2b(v.y); o.z = f2b(v.z); o.w = f2b(v.w);
    ((ushort4*)xb)[i] = o;
}

// ---------------- transpose+cast weights: W1[512][256]->w1t[256][512], W2[256][64]->w2t[64][256] ----------------
__global__ __launch_bounds__(256) void k_prep_w(const float* __restrict__ w1,
                                                const float* __restrict__ w2,
                                                unsigned short* __restrict__ w1t,
                                                unsigned short* __restrict__ w2t) {
    int b = blockIdx.x, tid = threadIdx.x;
    if (b < 8) {
        int c = tid;          // 0..255
        int k0 = b * 64;
        for (int kk = 0; kk < 64; kk += 8) {
            short8 v;
#pragma unroll
            for (int j = 0; j < 8; ++j) v[j] = (short)f2b(w1[(size_t)(k0 + kk + j) * HH + c]);
            *(short8*)&w1t[(size_t)c * DD + k0 + kk] = v;
        }
    } else {
        int c = tid & 63;
        int k0 = (b - 8) * 64 + (tid >> 6) * 16;
        for (int kk = 0; kk < 16; kk += 8) {
            short8 v;
#pragma unroll
            for (int j = 0; j < 8; ++j) v[j] = (short)f2b(w2[(size_t)(k0 + kk + j) * LL + c]);
            *(short8*)&w2t[(size_t)c * HH + k0 + kk] = v;
        }
    }
}

// ---------------- GEMM1 (MFMA): xw1b[N,H] = xb[N,D] @ W1 (via w1t), bf16 out ----------------
// grid (2, 64); block tile 128 rows x 128 cols; 4 waves 2x2, wave tile 64x64
__global__ __launch_bounds__(256) void k_gemm1_mfma(const unsigned short* __restrict__ xb,
                                                    const unsigned short* __restrict__ w1t,
                                                    unsigned short* __restrict__ xw1b) {
    const int tid = threadIdx.x;
    const int wave = tid >> 6, lane = tid & 63;
    const int wr = wave >> 1, wc = wave & 1;
    const int lm = lane & 15, lh = lane >> 4;
    const int r0 = blockIdx.y * 128 + wr * 64;
    const int c0 = blockIdx.x * 128 + wc * 64;

    f32x4 acc[4][4];
#pragma unroll
    for (int m = 0; m < 4; ++m)
#pragma unroll
        for (int n = 0; n < 4; ++n) acc[m][n] = (f32x4){0.f, 0.f, 0.f, 0.f};

    for (int k0 = 0; k0 < DD; k0 += 32) {
        short8 a[4], b[4];
#pragma unroll
        for (int m = 0; m < 4; ++m)
            a[m] = *(const short8*)&xb[(size_t)(r0 + m * 16 + lm) * DD + k0 + lh * 8];
#pragma unroll
        for (int n = 0; n < 4; ++n)
            b[n] = *(const short8*)&w1t[(size_t)(c0 + n * 16 + lm) * DD + k0 + lh * 8];
#pragma unroll
        for (int m = 0; m < 4; ++m)
#pragma unroll
            for (int n = 0; n < 4; ++n)
                acc[m][n] = __builtin_amdgcn_mfma_f32_16x16x32_bf16(a[m], b[n], acc[m][n], 0, 0, 0);
    }
#pragma unroll
    for (int m = 0; m < 4; ++m)
#pragma unroll
        for (int n = 0; n < 4; ++n)
#pragma unroll
            for (int q = 0; q < 4; ++q) {
                int row = r0 + m * 16 + lh * 4 + q;
                int col = c0 + n * 16 + lm;
                xw1b[(size_t)row * HH + col] = f2b(acc[m][n][q]);
            }
}

// ---------------- SpMM1 (bucketed, bf16): haccb[row] = bf16(relu(sum w * xw1b[col])) ----------------
__global__ __launch_bounds__(256) void k_spmm1_csr(const int* __restrict__ cnt,
                                                   const int* __restrict__ slotc,
                                                   const float* __restrict__ slotw,
                                                   const unsigned short* __restrict__ src,
                                                   unsigned short* __restrict__ dst) {
    const int tid = threadIdx.x;
    const int row = blockIdx.x * 4 + (tid >> 6);
    const int lane = tid & 63;
    const int deg = min(cnt[row], CAP);
    const int base = row * CAP;

    f32x4 acc = {0.f, 0.f, 0.f, 0.f};
    int i = 0;
    for (; i + 3 < deg; i += 4) {
        int4 c4 = *(const int4*)&slotc[base + i];
        float4 w4 = *(const float4*)&slotw[base + i];
        ushort4 u0 = *(const ushort4*)&src[(size_t)c4.x * HH + lane * 4];
        ushort4 u1 = *(const ushort4*)&src[(size_t)c4.y * HH + lane * 4];
        ushort4 u2 = *(const ushort4*)&src[(size_t)c4.z * HH + lane * 4];
        ushort4 u3 = *(const ushort4*)&src[(size_t)c4.w * HH + lane * 4];
        acc[0] = fmaf(w4.x, b2f(u0.x), acc[0]); acc[1] = fmaf(w4.x, b2f(u0.y), acc[1]);
        acc[2] = fmaf(w4.x, b2f(u0.z), acc[2]); acc[3] = fmaf(w4.x, b2f(u0.w), acc[3]);
        acc[0] = fmaf(w4.y, b2f(u1.x), acc[0]); acc[1] = fmaf(w4.y, b2f(u1.y), acc[1]);
        acc[2] = fmaf(w4.y, b2f(u1.z), acc[2]); acc[3] = fmaf(w4.y, b2f(u1.w), acc[3]);
        acc[0] = fmaf(w4.z, b2f(u2.x), acc[0]); acc[1] = fmaf(w4.z, b2f(u2.y), acc[1]);
        acc[2] = fmaf(w4.z, b2f(u2.z), acc[2]); acc[3] = fmaf(w4.z, b2f(u2.w), acc[3]);
        acc[0] = fmaf(w4.w, b2f(u3.x), acc[0]); acc[1] = fmaf(w4.w, b2f(u3.y), acc[1]);
        acc[2] = fmaf(w4.w, b2f(u3.z), acc[2]); acc[3] = fmaf(w4.w, b2f(u3.w), acc[3]);
    }
    for (; i < deg; ++i) {
        int c = slotc[base + i];
        float w = slotw[base + i];
        ushort4 u = *(const ushort4*)&src[(size_t)c * HH + lane * 4];
        acc[0] = fmaf(w, b2f(u.x), acc[0]); acc[1] = fmaf(w, b2f(u.y), acc[1]);
        acc[2] = fmaf(w, b2f(u.z), acc[2]); acc[3] = fmaf(w, b2f(u.w), acc[3]);
    }
    ushort4 o;
    o.x = f2b(fmaxf(acc[0], 0.f)); o.y = f2b(fmaxf(acc[1], 0.f));
    o.z = f2b(fmaxf(acc[2], 0.f)); o.w = f2b(fmaxf(acc[3], 0.f));
    *(ushort4*)&dst[(size_t)row * HH + lane * 4] = o;
}

// ---------------- GEMM2 (MFMA): hw2b[N,L] = haccb[N,H] @ W2 (via w2t), bf16 out ----------------
// grid 32; block tile 256 rows x 64 cols; wave owns 64 rows x 64 cols
__global__ __launch_bounds__(256) void k_gemm2_mfma(const unsigned short* __restrict__ haccb,
                                                    const unsigned short* __restrict__ w2t,
                                                    unsigned short* __restrict__ hw2b) {
    const int tid = threadIdx.x;
    const int wave = tid >> 6, lane = tid & 63;
    const int lm = lane & 15, lh = lane >> 4;
    const int r0 = blockIdx.x * 256 + wave * 64;

    f32x4 acc[4][4];
#pragma unroll
    for (int m = 0; m < 4; ++m)
#pragma unroll
        for (int n = 0; n < 4; ++n) acc[m][n] = (f32x4){0.f, 0.f, 0.f, 0.f};

    for (int k0 = 0; k0 < HH; k0 += 32) {
        short8 a[4], b[4];
#pragma unroll
        for (int m = 0; m < 4; ++m)
            a[m] = *(const short8*)&haccb[(size_t)(r0 + m * 16 + lm) * HH + k0 + lh * 8];
#pragma unroll
        for (int n = 0; n < 4; ++n)
            b[n] = *(const short8*)&w2t[(size_t)(n * 16 + lm) * HH + k0 + lh * 8];
#pragma unroll
        for (int m = 0; m < 4; ++m)
#pragma unroll
            for (int n = 0; n < 4; ++n)
                acc[m][n] = __builtin_amdgcn_mfma_f32_16x16x32_bf16(a[m], b[n], acc[m][n], 0, 0, 0);
    }
#pragma unroll
    for (int m = 0; m < 4; ++m)
#pragma unroll
        for (int n = 0; n < 4; ++n)
#pragma unroll
            for (int q = 0; q < 4; ++q) {
                int row = r0 + m * 16 + lh * 4 + q;
                int col = n * 16 + lm;
                hw2b[(size_t)row * LL + col] = f2b(acc[m][n][q]);
            }
}

// ---------------- SpMM2 (bucketed, bf16): zb[row] = bf16(relu(sum w * hw2b[col])) ----------------
__global__ __launch_bounds__(256) void k_spmm2_csr(const int* __restrict__ cnt,
                                                   const int* __restrict__ slotc,
                                                   const float* __restrict__ slotw,
                                                   const unsigned short* __restrict__ src,
                                                   unsigned short* __restrict__ zb) {
    const int tid = threadIdx.x;
    const int row = blockIdx.x * 4 + (tid >> 6);
    const int lane = tid & 63;
    const int deg = min(cnt[row], CAP);
    const int base = row * CAP;

    float acc = 0.f;
    int i = 0;
    for (; i + 3 < deg; i += 4) {
        int4 c4 = *(const int4*)&slotc[base + i];
        float4 w4 = *(const float4*)&slotw[base + i];
        float v0 = b2f(src[(size_t)c4.x * LL + lane]);
        float v1 = b2f(src[(size_t)c4.y * LL + lane]);
        float v2 = b2f(src[(size_t)c4.z * LL + lane]);
        float v3 = b2f(src[(size_t)c4.w * LL + lane]);
        acc = fmaf(w4.x, v0, acc);
        acc = fmaf(w4.y, v1, acc);
        acc = fmaf(w4.z, v2, acc);
        acc = fmaf(w4.w, v3, acc);
    }
    for (; i < deg; ++i) {
        int c = slotc[base + i];
        float w = slotw[base + i];
        acc = fmaf(w, b2f(src[(size_t)c * LL + lane]), acc);
    }
    zb[(size_t)row * LL + lane] = f2b(fmaxf(acc, 0.f));
}

// ---------------- decode: out = (sigmoid(z z^T) + F)*(1-2F), bf16 MFMA ----------------
__global__ __launch_bounds__(256) void k_decode(const unsigned short* __restrict__ zb,
                                                float* __restrict__ out) {
    const int tid = threadIdx.x;
    const int wave = tid >> 6, lane = tid & 63;
    const int bi = blockIdx.y, bj = blockIdx.x;
    const int wr = wave >> 1, wc = wave & 1;
    const int rA = bi * 64 + wr * 32;
    const int rB = bj * 64 + wc * 32;
    const int lm = lane & 15, lh = lane >> 4;

    short8 a[2][2], b[2][2];
#pragma unroll
    for (int m = 0; m < 2; ++m)
#pragma unroll
        for (int s = 0; s < 2; ++s) {
            a[m][s] = *(const short8*)&zb[(size_t)(rA + m * 16 + lm) * LL + s * 32 + lh * 8];
            b[m][s] = *(const short8*)&zb[(size_t)(rB + m * 16 + lm) * LL + s * 32 + lh * 8];
        }

    f32x4 acc[2][2];
#pragma unroll
    for (int m = 0; m < 2; ++m)
#pragma unroll
        for (int n = 0; n < 2; ++n)
            acc[m][n] = (f32x4){0.f, 0.f, 0.f, 0.f};

#pragma unroll
    for (int m = 0; m < 2; ++m)
#pragma unroll
        for (int n = 0; n < 2; ++n)
#pragma unroll
            for (int s = 0; s < 2; ++s)
                acc[m][n] = __builtin_amdgcn_mfma_f32_16x16x32_bf16(
                    a[m][s], b[n][s], acc[m][n], 0, 0, 0);

    const float SCALE = 1.0f - 2.0f * 1e-7f;
    const float BIAS = 1e-7f * SCALE;
#pragma unroll
    for (int m = 0; m < 2; ++m)
#pragma unroll
        for (int n = 0; n < 2; ++n)
#pragma unroll
            for (int q = 0; q < 4; ++q) {
                float xv = acc[m][n][q];
                float sig = 1.0f / (1.0f + __expf(-xv));
                float val = fmaf(sig, SCALE, BIAS);
                size_t row = rA + m * 16 + lh * 4 + q;
                size_t col = rB + n * 16 + lm;
                out[row * NN + col] = val;
            }
}

// ---------------- launch ----------------
extern "C" void kernel_launch(void* const* d_in, const int* in_sizes, int n_in,
                              void* d_out, int out_size, void* d_ws, size_t ws_size,
                              hipStream_t stream) {
    const float* x    = (const float*)d_in[0];
    const int*   erow = (const int*)d_in[1];
    const int*   ecol = (const int*)d_in[2];
    const float* ew   = (const float*)d_in[3];
    const float* w1   = (const float*)d_in[4];
    const float* w2   = (const float*)d_in[5];
    float* out = (float*)d_out;

    char* p = (char*)d_ws;
    unsigned short* xb    = (unsigned short*)p; p += (size_t)NN * DD * 2;  // 8 MB
    unsigned short* w1t   = (unsigned short*)p; p += (size_t)HH * DD * 2;  // 256 KB
    unsigned short* w2t   = (unsigned short*)p; p += (size_t)LL * HH * 2;  // 32 KB
    unsigned short* xw1b  = (unsigned short*)p; p += (size_t)NN * HH * 2;  // 4 MB
    unsigned short* haccb = (unsigned short*)p; p += (size_t)NN * HH * 2;  // 4 MB
    unsigned short* hw2b  = (unsigned short*)p; p += (size_t)NN * LL * 2;  // 1 MB
    unsigned short* zb    = (unsigned short*)p; p += (size_t)NN * LL * 2;  // 1 MB
    int*   cnt   = (int*)p;   p += (size_t)NN * 4;        // 32 KB
    int*   slotc = (int*)p;   p += (size_t)NN * CAP * 4;  // 3 MB
    float* slotw = (float*)p; p += (size_t)NN * CAP * 4;  // 3 MB

    k_zero_cnt<<<NN / 256, 256, 0, stream>>>(cnt);
    k_bucket<<<EE / 256, 256, 0, stream>>>(erow, ecol, ew, cnt, slotc, slotw);
    k_cast_x<<<NN * DD / 4 / 256, 256, 0, stream>>>(x, xb, NN * DD / 4);
    k_prep_w<<<12, 256, 0, stream>>>(w1, w2, w1t, w2t);
    k_gemm1_mfma<<<dim3(2, 64), 256, 0, stream>>>(xb, w1t, xw1b);
    k_spmm1_csr<<<NN / 4, 256, 0, stream>>>(cnt, slotc, slotw, xw1b, haccb);
    k_gemm2_mfma<<<32, 256, 0, stream>>>(haccb, w2t, hw2b);
    k_spmm2_csr<<<NN / 4, 256, 0, stream>>>(cnt, slotc, slotw, hw2b, zb);
    k_decode<<<dim3(128, 128), 256, 0, stream>>>(zb, out);
}

// Round 5
// 150.778 us; speedup vs baseline: 8.1304x; 1.1070x over previous
//
#include <hip/hip_runtime.h>
#include <hip/hip_bf16.h>

#define NN 8192
#define DD 512
#define HH 256
#define LL 64
#define EE 262144
#define CAP 96
#define LSTR 68   // decode LDS row stride (floats)

typedef __attribute__((ext_vector_type(8))) short short8;
typedef __attribute__((ext_vector_type(4))) float f32x4;

__device__ __forceinline__ unsigned short f2b(float f) {
    __hip_bfloat16 b = __float2bfloat16(f);
    return *(unsigned short*)&b;
}
__device__ __forceinline__ float b2f(unsigned short u) {
    union { unsigned int i; float f; } c; c.i = ((unsigned int)u) << 16; return c.f;
}

// ---------------- prep: zero cnt + cast x->bf16 + transpose/cast W1,W2 ----------------
// grid 2048 x 256
__global__ __launch_bounds__(256) void k_prep(const float* __restrict__ x,
                                              const float* __restrict__ w1,
                                              const float* __restrict__ w2,
                                              unsigned short* __restrict__ xb,
                                              unsigned short* __restrict__ w1t,
                                              unsigned short* __restrict__ w2t,
                                              int* __restrict__ cnt) {
    const int gtid = blockIdx.x * 256 + threadIdx.x;  // 0..524287
#pragma unroll
    for (int it = 0; it < 2; ++it) {
        int i = gtid + it * 524288;
        float4 v = ((const float4*)x)[i];
        ushort4 o; o.x = f2b(v.x); o.y = f2b(v.y); o.z = f2b(v.z); o.w = f2b(v.w);
        ((ushort4*)xb)[i] = o;
    }
    if (gtid < NN / 4) ((int4*)cnt)[gtid] = make_int4(0, 0, 0, 0);
    if (gtid < 16384) {  // w1t[256][512]
        int c = gtid & 255, kg = gtid >> 8;
        short8 v;
#pragma unroll
        for (int j = 0; j < 8; ++j) v[j] = (short)f2b(w1[(size_t)(kg * 8 + j) * HH + c]);
        *(short8*)&w1t[(size_t)c * DD + kg * 8] = v;
    }
    if (gtid < 2048) {   // w2t[64][256]
        int c = gtid & 63, kg = gtid >> 6;
        short8 v;
#pragma unroll
        for (int j = 0; j < 8; ++j) v[j] = (short)f2b(w2[(size_t)(kg * 8 + j) * LL + c]);
        *(short8*)&w2t[(size_t)c * HH + kg * 8] = v;
    }
}

// ---------------- bucket edges by row ----------------
__global__ __launch_bounds__(256) void k_bucket(const int* __restrict__ erow,
                                                const int* __restrict__ ecol,
                                                const float* __restrict__ ew,
                                                int* __restrict__ cnt,
                                                int* __restrict__ slotc,
                                                float* __restrict__ slotw) {
    int e = blockIdx.x * 256 + threadIdx.x;
    if (e >= EE) return;
    int r = erow[e];
    int pos = atomicAdd(&cnt[r], 1);
    if (pos < CAP) {
        slotc[r * CAP + pos] = ecol[e];
        slotw[r * CAP + pos] = ew[e];
    }
}

// ---------------- GEMM1 (MFMA): xw1b[N,H] = xb[N,D] @ W1 (via w1t), bf16 out ----------------
__global__ __launch_bounds__(256) void k_gemm1_mfma(const unsigned short* __restrict__ xb,
                                                    const unsigned short* __restrict__ w1t,
                                                    unsigned short* __restrict__ xw1b) {
    const int tid = threadIdx.x;
    const int wave = tid >> 6, lane = tid & 63;
    const int wr = wave >> 1, wc = wave & 1;
    const int lm = lane & 15, lh = lane >> 4;
    const int r0 = blockIdx.y * 128 + wr * 64;
    const int c0 = blockIdx.x * 128 + wc * 64;

    f32x4 acc[4][4];
#pragma unroll
    for (int m = 0; m < 4; ++m)
#pragma unroll
        for (int n = 0; n < 4; ++n) acc[m][n] = (f32x4){0.f, 0.f, 0.f, 0.f};

    for (int k0 = 0; k0 < DD; k0 += 32) {
        short8 a[4], b[4];
#pragma unroll
        for (int m = 0; m < 4; ++m)
            a[m] = *(const short8*)&xb[(size_t)(r0 + m * 16 + lm) * DD + k0 + lh * 8];
#pragma unroll
        for (int n = 0; n < 4; ++n)
            b[n] = *(const short8*)&w1t[(size_t)(c0 + n * 16 + lm) * DD + k0 + lh * 8];
#pragma unroll
        for (int m = 0; m < 4; ++m)
#pragma unroll
            for (int n = 0; n < 4; ++n)
                acc[m][n] = __builtin_amdgcn_mfma_f32_16x16x32_bf16(a[m], b[n], acc[m][n], 0, 0, 0);
    }
#pragma unroll
    for (int m = 0; m < 4; ++m)
#pragma unroll
        for (int n = 0; n < 4; ++n)
#pragma unroll
            for (int q = 0; q < 4; ++q) {
                int row = r0 + m * 16 + lh * 4 + q;
                int col = c0 + n * 16 + lm;
                xw1b[(size_t)row * HH + col] = f2b(acc[m][n][q]);
            }
}

// ---------------- SpMM1 (bucketed, bf16) ----------------
__global__ __launch_bounds__(256) void k_spmm1_csr(const int* __restrict__ cnt,
                                                   const int* __restrict__ slotc,
                                                   const float* __restrict__ slotw,
                                                   const unsigned short* __restrict__ src,
                                                   unsigned short* __restrict__ dst) {
    const int tid = threadIdx.x;
    const int row = blockIdx.x * 4 + (tid >> 6);
    const int lane = tid & 63;
    const int deg = min(cnt[row], CAP);
    const int base = row * CAP;

    f32x4 acc = {0.f, 0.f, 0.f, 0.f};
    int i = 0;
    for (; i + 3 < deg; i += 4) {
        int4 c4 = *(const int4*)&slotc[base + i];
        float4 w4 = *(const float4*)&slotw[base + i];
        ushort4 u0 = *(const ushort4*)&src[(size_t)c4.x * HH + lane * 4];
        ushort4 u1 = *(const ushort4*)&src[(size_t)c4.y * HH + lane * 4];
        ushort4 u2 = *(const ushort4*)&src[(size_t)c4.z * HH + lane * 4];
        ushort4 u3 = *(const ushort4*)&src[(size_t)c4.w * HH + lane * 4];
        acc[0] = fmaf(w4.x, b2f(u0.x), acc[0]); acc[1] = fmaf(w4.x, b2f(u0.y), acc[1]);
        acc[2] = fmaf(w4.x, b2f(u0.z), acc[2]); acc[3] = fmaf(w4.x, b2f(u0.w), acc[3]);
        acc[0] = fmaf(w4.y, b2f(u1.x), acc[0]); acc[1] = fmaf(w4.y, b2f(u1.y), acc[1]);
        acc[2] = fmaf(w4.y, b2f(u1.z), acc[2]); acc[3] = fmaf(w4.y, b2f(u1.w), acc[3]);
        acc[0] = fmaf(w4.z, b2f(u2.x), acc[0]); acc[1] = fmaf(w4.z, b2f(u2.y), acc[1]);
        acc[2] = fmaf(w4.z, b2f(u2.z), acc[2]); acc[3] = fmaf(w4.z, b2f(u2.w), acc[3]);
        acc[0] = fmaf(w4.w, b2f(u3.x), acc[0]); acc[1] = fmaf(w4.w, b2f(u3.y), acc[1]);
        acc[2] = fmaf(w4.w, b2f(u3.z), acc[2]); acc[3] = fmaf(w4.w, b2f(u3.w), acc[3]);
    }
    for (; i < deg; ++i) {
        int c = slotc[base + i];
        float w = slotw[base + i];
        ushort4 u = *(const ushort4*)&src[(size_t)c * HH + lane * 4];
        acc[0] = fmaf(w, b2f(u.x), acc[0]); acc[1] = fmaf(w, b2f(u.y), acc[1]);
        acc[2] = fmaf(w, b2f(u.z), acc[2]); acc[3] = fmaf(w, b2f(u.w), acc[3]);
    }
    ushort4 o;
    o.x = f2b(fmaxf(acc[0], 0.f)); o.y = f2b(fmaxf(acc[1], 0.f));
    o.z = f2b(fmaxf(acc[2], 0.f)); o.w = f2b(fmaxf(acc[3], 0.f));
    *(ushort4*)&dst[(size_t)row * HH + lane * 4] = o;
}

// ---------------- GEMM2 (MFMA): hw2b[N,L] = haccb[N,H] @ W2 (via w2t), bf16 out ----------------
__global__ __launch_bounds__(256) void k_gemm2_mfma(const unsigned short* __restrict__ haccb,
                                                    const unsigned short* __restrict__ w2t,
                                                    unsigned short* __restrict__ hw2b) {
    const int tid = threadIdx.x;
    const int wave = tid >> 6, lane = tid & 63;
    const int lm = lane & 15, lh = lane >> 4;
    const int r0 = blockIdx.x * 256 + wave * 64;

    f32x4 acc[4][4];
#pragma unroll
    for (int m = 0; m < 4; ++m)
#pragma unroll
        for (int n = 0; n < 4; ++n) acc[m][n] = (f32x4){0.f, 0.f, 0.f, 0.f};

    for (int k0 = 0; k0 < HH; k0 += 32) {
        short8 a[4], b[4];
#pragma unroll
        for (int m = 0; m < 4; ++m)
            a[m] = *(const short8*)&haccb[(size_t)(r0 + m * 16 + lm) * HH + k0 + lh * 8];
#pragma unroll
        for (int n = 0; n < 4; ++n)
            b[n] = *(const short8*)&w2t[(size_t)(n * 16 + lm) * HH + k0 + lh * 8];
#pragma unroll
        for (int m = 0; m < 4; ++m)
#pragma unroll
            for (int n = 0; n < 4; ++n)
                acc[m][n] = __builtin_amdgcn_mfma_f32_16x16x32_bf16(a[m], b[n], acc[m][n], 0, 0, 0);
    }
#pragma unroll
    for (int m = 0; m < 4; ++m)
#pragma unroll
        for (int n = 0; n < 4; ++n)
#pragma unroll
            for (int q = 0; q < 4; ++q) {
                int row = r0 + m * 16 + lh * 4 + q;
                int col = n * 16 + lm;
                hw2b[(size_t)row * LL + col] = f2b(acc[m][n][q]);
            }
}

// ---------------- SpMM2 (bucketed, bf16) ----------------
__global__ __launch_bounds__(256) void k_spmm2_csr(const int* __restrict__ cnt,
                                                   const int* __restrict__ slotc,
                                                   const float* __restrict__ slotw,
                                                   const unsigned short* __restrict__ src,
                                                   unsigned short* __restrict__ zb) {
    const int tid = threadIdx.x;
    const int row = blockIdx.x * 4 + (tid >> 6);
    const int lane = tid & 63;
    const int deg = min(cnt[row], CAP);
    const int base = row * CAP;

    float acc = 0.f;
    int i = 0;
    for (; i + 3 < deg; i += 4) {
        int4 c4 = *(const int4*)&slotc[base + i];
        float4 w4 = *(const float4*)&slotw[base + i];
        float v0 = b2f(src[(size_t)c4.x * LL + lane]);
        float v1 = b2f(src[(size_t)c4.y * LL + lane]);
        float v2 = b2f(src[(size_t)c4.z * LL + lane]);
        float v3 = b2f(src[(size_t)c4.w * LL + lane]);
        acc = fmaf(w4.x, v0, acc);
        acc = fmaf(w4.y, v1, acc);
        acc = fmaf(w4.z, v2, acc);
        acc = fmaf(w4.w, v3, acc);
    }
    for (; i < deg; ++i) {
        int c = slotc[base + i];
        float w = slotw[base + i];
        acc = fmaf(w, b2f(src[(size_t)c * LL + lane]), acc);
    }
    zb[(size_t)row * LL + lane] = f2b(fmaxf(acc, 0.f));
}

// ---------------- decode: MFMA + LDS-coalesced nontemporal store ----------------
__global__ __launch_bounds__(256) void k_decode(const unsigned short* __restrict__ zb,
                                                float* __restrict__ out) {
    __shared__ float ls[64 * LSTR];
    const int tid = threadIdx.x;
    const int wave = tid >> 6, lane = tid & 63;
    const int bi = blockIdx.y, bj = blockIdx.x;
    const int wr = wave >> 1, wc = wave & 1;
    const int rA = bi * 64 + wr * 32;
    const int rB = bj * 64 + wc * 32;
    const int lm = lane & 15, lh = lane >> 4;

    short8 a[2][2], b[2][2];
#pragma unroll
    for (int m = 0; m < 2; ++m)
#pragma unroll
        for (int s = 0; s < 2; ++s) {
            a[m][s] = *(const short8*)&zb[(size_t)(rA + m * 16 + lm) * LL + s * 32 + lh * 8];
            b[m][s] = *(const short8*)&zb[(size_t)(rB + m * 16 + lm) * LL + s * 32 + lh * 8];
        }

    f32x4 acc[2][2];
#pragma unroll
    for (int m = 0; m < 2; ++m)
#pragma unroll
        for (int n = 0; n < 2; ++n)
            acc[m][n] = (f32x4){0.f, 0.f, 0.f, 0.f};

#pragma unroll
    for (int m = 0; m < 2; ++m)
#pragma unroll
        for (int n = 0; n < 2; ++n)
#pragma unroll
            for (int s = 0; s < 2; ++s)
                acc[m][n] = __builtin_amdgcn_mfma_f32_16x16x32_bf16(
                    a[m][s], b[n][s], acc[m][n], 0, 0, 0);

    const float SCALE = 1.0f - 2.0f * 1e-7f;
    const float BIAS = 1e-7f * SCALE;
#pragma unroll
    for (int m = 0; m < 2; ++m)
#pragma unroll
        for (int n = 0; n < 2; ++n)
#pragma unroll
            for (int q = 0; q < 4; ++q) {
                float xv = acc[m][n][q];
                float sig = 1.0f / (1.0f + __expf(-xv));
                float val = fmaf(sig, SCALE, BIAS);
                int lr = wr * 32 + m * 16 + lh * 4 + q;
                int lc = wc * 32 + n * 16 + lm;
                ls[lr * LSTR + lc] = val;
            }
    __syncthreads();

    const int rr = tid >> 4;           // 0..15
    const int cc = (tid & 15) * 4;     // 0..60
    const size_t base = (size_t)(bi * 64) * NN + bj * 64;
#pragma unroll
    for (int rg = 0; rg < 4; ++rg) {
        int row = rg * 16 + rr;
        f32x4 v = *(const f32x4*)&ls[row * LSTR + cc];
        __builtin_nontemporal_store(v, (f32x4*)&out[base + (size_t)row * NN + cc]);
    }
}

// ---------------- launch ----------------
extern "C" void kernel_launch(void* const* d_in, const int* in_sizes, int n_in,
                              void* d_out, int out_size, void* d_ws, size_t ws_size,
                              hipStream_t stream) {
    const float* x    = (const float*)d_in[0];
    const int*   erow = (const int*)d_in[1];
    const int*   ecol = (const int*)d_in[2];
    const float* ew   = (const float*)d_in[3];
    const float* w1   = (const float*)d_in[4];
    const float* w2   = (const float*)d_in[5];
    float* out = (float*)d_out;

    char* p = (char*)d_ws;
    unsigned short* xb    = (unsigned short*)p; p += (size_t)NN * DD * 2;  // 8 MB
    unsigned short* w1t   = (unsigned short*)p; p += (size_t)HH * DD * 2;  // 256 KB
    unsigned short* w2t   = (unsigned short*)p; p += (size_t)LL * HH * 2;  // 32 KB
    unsigned short* xw1b  = (unsigned short*)p; p += (size_t)NN * HH * 2;  // 4 MB
    unsigned short* haccb = (unsigned short*)p; p += (size_t)NN * HH * 2;  // 4 MB
    unsigned short* hw2b  = (unsigned short*)p; p += (size_t)NN * LL * 2;  // 1 MB
    unsigned short* zb    = (unsigned short*)p; p += (size_t)NN * LL * 2;  // 1 MB
    int*   cnt   = (int*)p;   p += (size_t)NN * 4;        // 32 KB
    int*   slotc = (int*)p;   p += (size_t)NN * CAP * 4;  // 3 MB
    float* slotw = (float*)p; p += (size_t)NN * CAP * 4;  // 3 MB

    k_prep<<<2048, 256, 0, stream>>>(x, w1, w2, xb, w1t, w2t, cnt);
    k_bucket<<<EE / 256, 256, 0, stream>>>(erow, ecol, ew, cnt, slotc, slotw);
    k_gemm1_mfma<<<dim3(2, 64), 256, 0, stream>>>(xb, w1t, xw1b);
    k_spmm1_csr<<<NN / 4, 256, 0, stream>>>(cnt, slotc, slotw, xw1b, haccb);
    k_gemm2_mfma<<<32, 256, 0, stream>>>(haccb, w2t, hw2b);
    k_spmm2_csr<<<NN / 4, 256, 0, stream>>>(cnt, slotc, slotw, hw2b, zb);
    k_decode<<<dim3(128, 128), 256, 0, stream>>>(zb, out);
}

// Round 6
// 131.014 us; speedup vs baseline: 9.3569x; 1.1509x over previous
//
#include <hip/hip_runtime.h>
#include <hip/hip_bf16.h>

#define NN 8192
#define DD 512
#define HH 256
#define LL 64
#define EE 262144
#define CAP 96
#define DSTR 260   // decode LDS row stride (floats): 64x260 f32 = 65 KB

typedef __attribute__((ext_vector_type(8))) short short8;
typedef __attribute__((ext_vector_type(4))) float f32x4;

__device__ __forceinline__ unsigned short f2b(float f) {
    __hip_bfloat16 b = __float2bfloat16(f);
    return *(unsigned short*)&b;
}
__device__ __forceinline__ float b2f(unsigned short u) {
    union { unsigned int i; float f; } c; c.i = ((unsigned int)u) << 16; return c.f;
}

// ---------------- prep: zero cnt + cast x->bf16 + transpose/cast W1,W2 ----------------
__global__ __launch_bounds__(256) void k_prep(const float* __restrict__ x,
                                              const float* __restrict__ w1,
                                              const float* __restrict__ w2,
                                              unsigned short* __restrict__ xb,
                                              unsigned short* __restrict__ w1t,
                                              unsigned short* __restrict__ w2t,
                                              int* __restrict__ cnt) {
    const int gtid = blockIdx.x * 256 + threadIdx.x;  // 0..524287
#pragma unroll
    for (int it = 0; it < 2; ++it) {
        int i = gtid + it * 524288;
        float4 v = ((const float4*)x)[i];
        ushort4 o; o.x = f2b(v.x); o.y = f2b(v.y); o.z = f2b(v.z); o.w = f2b(v.w);
        ((ushort4*)xb)[i] = o;
    }
    if (gtid < NN / 4) ((int4*)cnt)[gtid] = make_int4(0, 0, 0, 0);
    if (gtid < 16384) {  // w1t[256][512]
        int c = gtid & 255, kg = gtid >> 8;
        short8 v;
#pragma unroll
        for (int j = 0; j < 8; ++j) v[j] = (short)f2b(w1[(size_t)(kg * 8 + j) * HH + c]);
        *(short8*)&w1t[(size_t)c * DD + kg * 8] = v;
    }
    if (gtid < 2048) {   // w2t[64][256]
        int c = gtid & 63, kg = gtid >> 6;
        short8 v;
#pragma unroll
        for (int j = 0; j < 8; ++j) v[j] = (short)f2b(w2[(size_t)(kg * 8 + j) * LL + c]);
        *(short8*)&w2t[(size_t)c * HH + kg * 8] = v;
    }
}

// ---------------- bucket edges by row ----------------
__global__ __launch_bounds__(256) void k_bucket(const int* __restrict__ erow,
                                                const int* __restrict__ ecol,
                                                const float* __restrict__ ew,
                                                int* __restrict__ cnt,
                                                int* __restrict__ slotc,
                                                float* __restrict__ slotw) {
    int e = blockIdx.x * 256 + threadIdx.x;
    if (e >= EE) return;
    int r = erow[e];
    int pos = atomicAdd(&cnt[r], 1);
    if (pos < CAP) {
        slotc[r * CAP + pos] = ecol[e];
        slotw[r * CAP + pos] = ew[e];
    }
}

// ---------------- GEMM1 (MFMA): xw1b[N,H] = xb[N,D] @ W1 (via w1t) ----------------
// grid (2,128): 256 blocks, tile 64 rows x 128 cols; wave = 32x64
__global__ __launch_bounds__(256) void k_gemm1_mfma(const unsigned short* __restrict__ xb,
                                                    const unsigned short* __restrict__ w1t,
                                                    unsigned short* __restrict__ xw1b) {
    const int tid = threadIdx.x;
    const int wave = tid >> 6, lane = tid & 63;
    const int wr = wave >> 1, wc = wave & 1;
    const int lm = lane & 15, lh = lane >> 4;
    const int r0 = blockIdx.y * 64 + wr * 32;
    const int c0 = blockIdx.x * 128 + wc * 64;

    f32x4 acc[2][4];
#pragma unroll
    for (int m = 0; m < 2; ++m)
#pragma unroll
        for (int n = 0; n < 4; ++n) acc[m][n] = (f32x4){0.f, 0.f, 0.f, 0.f};

    for (int k0 = 0; k0 < DD; k0 += 32) {
        short8 a[2], b[4];
#pragma unroll
        for (int m = 0; m < 2; ++m)
            a[m] = *(const short8*)&xb[(size_t)(r0 + m * 16 + lm) * DD + k0 + lh * 8];
#pragma unroll
        for (int n = 0; n < 4; ++n)
            b[n] = *(const short8*)&w1t[(size_t)(c0 + n * 16 + lm) * DD + k0 + lh * 8];
#pragma unroll
        for (int m = 0; m < 2; ++m)
#pragma unroll
            for (int n = 0; n < 4; ++n)
                acc[m][n] = __builtin_amdgcn_mfma_f32_16x16x32_bf16(a[m], b[n], acc[m][n], 0, 0, 0);
    }
#pragma unroll
    for (int m = 0; m < 2; ++m)
#pragma unroll
        for (int n = 0; n < 4; ++n)
#pragma unroll
            for (int q = 0; q < 4; ++q) {
                int row = r0 + m * 16 + lh * 4 + q;
                int col = c0 + n * 16 + lm;
                xw1b[(size_t)row * HH + col] = f2b(acc[m][n][q]);
            }
}

// ---------------- SpMM1 (bucketed, bf16, unroll 8) ----------------
__global__ __launch_bounds__(256) void k_spmm1_csr(const int* __restrict__ cnt,
                                                   const int* __restrict__ slotc,
                                                   const float* __restrict__ slotw,
                                                   const unsigned short* __restrict__ src,
                                                   unsigned short* __restrict__ dst) {
    const int tid = threadIdx.x;
    const int row = blockIdx.x * 4 + (tid >> 6);
    const int lane = tid & 63;
    const int deg = min(cnt[row], CAP);
    const int base = row * CAP;

    f32x4 acc = {0.f, 0.f, 0.f, 0.f};
    int i = 0;
    for (; i + 7 < deg; i += 8) {
        int4 ca = *(const int4*)&slotc[base + i];
        int4 cb = *(const int4*)&slotc[base + i + 4];
        float4 wa = *(const float4*)&slotw[base + i];
        float4 wb = *(const float4*)&slotw[base + i + 4];
        ushort4 u0 = *(const ushort4*)&src[(size_t)ca.x * HH + lane * 4];
        ushort4 u1 = *(const ushort4*)&src[(size_t)ca.y * HH + lane * 4];
        ushort4 u2 = *(const ushort4*)&src[(size_t)ca.z * HH + lane * 4];
        ushort4 u3 = *(const ushort4*)&src[(size_t)ca.w * HH + lane * 4];
        ushort4 u4 = *(const ushort4*)&src[(size_t)cb.x * HH + lane * 4];
        ushort4 u5 = *(const ushort4*)&src[(size_t)cb.y * HH + lane * 4];
        ushort4 u6 = *(const ushort4*)&src[(size_t)cb.z * HH + lane * 4];
        ushort4 u7 = *(const ushort4*)&src[(size_t)cb.w * HH + lane * 4];
        acc[0] = fmaf(wa.x, b2f(u0.x), acc[0]); acc[1] = fmaf(wa.x, b2f(u0.y), acc[1]);
        acc[2] = fmaf(wa.x, b2f(u0.z), acc[2]); acc[3] = fmaf(wa.x, b2f(u0.w), acc[3]);
        acc[0] = fmaf(wa.y, b2f(u1.x), acc[0]); acc[1] = fmaf(wa.y, b2f(u1.y), acc[1]);
        acc[2] = fmaf(wa.y, b2f(u1.z), acc[2]); acc[3] = fmaf(wa.y, b2f(u1.w), acc[3]);
        acc[0] = fmaf(wa.z, b2f(u2.x), acc[0]); acc[1] = fmaf(wa.z, b2f(u2.y), acc[1]);
        acc[2] = fmaf(wa.z, b2f(u2.z), acc[2]); acc[3] = fmaf(wa.z, b2f(u2.w), acc[3]);
        acc[0] = fmaf(wa.w, b2f(u3.x), acc[0]); acc[1] = fmaf(wa.w, b2f(u3.y), acc[1]);
        acc[2] = fmaf(wa.w, b2f(u3.z), acc[2]); acc[3] = fmaf(wa.w, b2f(u3.w), acc[3]);
        acc[0] = fmaf(wb.x, b2f(u4.x), acc[0]); acc[1] = fmaf(wb.x, b2f(u4.y), acc[1]);
        acc[2] = fmaf(wb.x, b2f(u4.z), acc[2]); acc[3] = fmaf(wb.x, b2f(u4.w), acc[3]);
        acc[0] = fmaf(wb.y, b2f(u5.x), acc[0]); acc[1] = fmaf(wb.y, b2f(u5.y), acc[1]);
        acc[2] = fmaf(wb.y, b2f(u5.z), acc[2]); acc[3] = fmaf(wb.y, b2f(u5.w), acc[3]);
        acc[0] = fmaf(wb.z, b2f(u6.x), acc[0]); acc[1] = fmaf(wb.z, b2f(u6.y), acc[1]);
        acc[2] = fmaf(wb.z, b2f(u6.z), acc[2]); acc[3] = fmaf(wb.z, b2f(u6.w), acc[3]);
        acc[0] = fmaf(wb.w, b2f(u7.x), acc[0]); acc[1] = fmaf(wb.w, b2f(u7.y), acc[1]);
        acc[2] = fmaf(wb.w, b2f(u7.z), acc[2]); acc[3] = fmaf(wb.w, b2f(u7.w), acc[3]);
    }
    for (; i + 3 < deg; i += 4) {
        int4 c4 = *(const int4*)&slotc[base + i];
        float4 w4 = *(const float4*)&slotw[base + i];
        ushort4 u0 = *(const ushort4*)&src[(size_t)c4.x * HH + lane * 4];
        ushort4 u1 = *(const ushort4*)&src[(size_t)c4.y * HH + lane * 4];
        ushort4 u2 = *(const ushort4*)&src[(size_t)c4.z * HH + lane * 4];
        ushort4 u3 = *(const ushort4*)&src[(size_t)c4.w * HH + lane * 4];
        acc[0] = fmaf(w4.x, b2f(u0.x), acc[0]); acc[1] = fmaf(w4.x, b2f(u0.y), acc[1]);
        acc[2] = fmaf(w4.x, b2f(u0.z), acc[2]); acc[3] = fmaf(w4.x, b2f(u0.w), acc[3]);
        acc[0] = fmaf(w4.y, b2f(u1.x), acc[0]); acc[1] = fmaf(w4.y, b2f(u1.y), acc[1]);
        acc[2] = fmaf(w4.y, b2f(u1.z), acc[2]); acc[3] = fmaf(w4.y, b2f(u1.w), acc[3]);
        acc[0] = fmaf(w4.z, b2f(u2.x), acc[0]); acc[1] = fmaf(w4.z, b2f(u2.y), acc[1]);
        acc[2] = fmaf(w4.z, b2f(u2.z), acc[2]); acc[3] = fmaf(w4.z, b2f(u2.w), acc[3]);
        acc[0] = fmaf(w4.w, b2f(u3.x), acc[0]); acc[1] = fmaf(w4.w, b2f(u3.y), acc[1]);
        acc[2] = fmaf(w4.w, b2f(u3.z), acc[2]); acc[3] = fmaf(w4.w, b2f(u3.w), acc[3]);
    }
    for (; i < deg; ++i) {
        int c = slotc[base + i];
        float w = slotw[base + i];
        ushort4 u = *(const ushort4*)&src[(size_t)c * HH + lane * 4];
        acc[0] = fmaf(w, b2f(u.x), acc[0]); acc[1] = fmaf(w, b2f(u.y), acc[1]);
        acc[2] = fmaf(w, b2f(u.z), acc[2]); acc[3] = fmaf(w, b2f(u.w), acc[3]);
    }
    ushort4 o;
    o.x = f2b(fmaxf(acc[0], 0.f)); o.y = f2b(fmaxf(acc[1], 0.f));
    o.z = f2b(fmaxf(acc[2], 0.f)); o.w = f2b(fmaxf(acc[3], 0.f));
    *(ushort4*)&dst[(size_t)row * HH + lane * 4] = o;
}

// ---------------- GEMM2 (MFMA): hw2b[N,L] = haccb[N,H] @ W2 (via w2t) ----------------
__global__ __launch_bounds__(256) void k_gemm2_mfma(const unsigned short* __restrict__ haccb,
                                                    const unsigned short* __restrict__ w2t,
                                                    unsigned short* __restrict__ hw2b) {
    const int tid = threadIdx.x;
    const int wave = tid >> 6, lane = tid & 63;
    const int lm = lane & 15, lh = lane >> 4;
    const int r0 = blockIdx.x * 256 + wave * 64;

    f32x4 acc[4][4];
#pragma unroll
    for (int m = 0; m < 4; ++m)
#pragma unroll
        for (int n = 0; n < 4; ++n) acc[m][n] = (f32x4){0.f, 0.f, 0.f, 0.f};

    for (int k0 = 0; k0 < HH; k0 += 32) {
        short8 a[4], b[4];
#pragma unroll
        for (int m = 0; m < 4; ++m)
            a[m] = *(const short8*)&haccb[(size_t)(r0 + m * 16 + lm) * HH + k0 + lh * 8];
#pragma unroll
        for (int n = 0; n < 4; ++n)
            b[n] = *(const short8*)&w2t[(size_t)(n * 16 + lm) * HH + k0 + lh * 8];
#pragma unroll
        for (int m = 0; m < 4; ++m)
#pragma unroll
            for (int n = 0; n < 4; ++n)
                acc[m][n] = __builtin_amdgcn_mfma_f32_16x16x32_bf16(a[m], b[n], acc[m][n], 0, 0, 0);
    }
#pragma unroll
    for (int m = 0; m < 4; ++m)
#pragma unroll
        for (int n = 0; n < 4; ++n)
#pragma unroll
            for (int q = 0; q < 4; ++q) {
                int row = r0 + m * 16 + lh * 4 + q;
                int col = n * 16 + lm;
                hw2b[(size_t)row * LL + col] = f2b(acc[m][n][q]);
            }
}

// ---------------- SpMM2 (bucketed, bf16, unroll 8) ----------------
__global__ __launch_bounds__(256) void k_spmm2_csr(const int* __restrict__ cnt,
                                                   const int* __restrict__ slotc,
                                                   const float* __restrict__ slotw,
                                                   const unsigned short* __restrict__ src,
                                                   unsigned short* __restrict__ zb) {
    const int tid = threadIdx.x;
    const int row = blockIdx.x * 4 + (tid >> 6);
    const int lane = tid & 63;
    const int deg = min(cnt[row], CAP);
    const int base = row * CAP;

    float acc = 0.f;
    int i = 0;
    for (; i + 7 < deg; i += 8) {
        int4 ca = *(const int4*)&slotc[base + i];
        int4 cb = *(const int4*)&slotc[base + i + 4];
        float4 wa = *(const float4*)&slotw[base + i];
        float4 wb = *(const float4*)&slotw[base + i + 4];
        float v0 = b2f(src[(size_t)ca.x * LL + lane]);
        float v1 = b2f(src[(size_t)ca.y * LL + lane]);
        float v2 = b2f(src[(size_t)ca.z * LL + lane]);
        float v3 = b2f(src[(size_t)ca.w * LL + lane]);
        float v4 = b2f(src[(size_t)cb.x * LL + lane]);
        float v5 = b2f(src[(size_t)cb.y * LL + lane]);
        float v6 = b2f(src[(size_t)cb.z * LL + lane]);
        float v7 = b2f(src[(size_t)cb.w * LL + lane]);
        acc = fmaf(wa.x, v0, acc); acc = fmaf(wa.y, v1, acc);
        acc = fmaf(wa.z, v2, acc); acc = fmaf(wa.w, v3, acc);
        acc = fmaf(wb.x, v4, acc); acc = fmaf(wb.y, v5, acc);
        acc = fmaf(wb.z, v6, acc); acc = fmaf(wb.w, v7, acc);
    }
    for (; i + 3 < deg; i += 4) {
        int4 c4 = *(const int4*)&slotc[base + i];
        float4 w4 = *(const float4*)&slotw[base + i];
        float v0 = b2f(src[(size_t)c4.x * LL + lane]);
        float v1 = b2f(src[(size_t)c4.y * LL + lane]);
        float v2 = b2f(src[(size_t)c4.z * LL + lane]);
        float v3 = b2f(src[(size_t)c4.w * LL + lane]);
        acc = fmaf(w4.x, v0, acc); acc = fmaf(w4.y, v1, acc);
        acc = fmaf(w4.z, v2, acc); acc = fmaf(w4.w, v3, acc);
    }
    for (; i < deg; ++i) {
        int c = slotc[base + i];
        float w = slotw[base + i];
        acc = fmaf(w, b2f(src[(size_t)c * LL + lane]), acc);
    }
    zb[(size_t)row * LL + lane] = f2b(fmaxf(acc, 0.f));
}

// ---------------- decode: 64x256 tiles, MFMA + LDS stage + 1KB-contiguous NT stores ----------------
// grid (32, 128): bj = 256-col strip, bi = 64-row strip; wave = 64 rows x 64 cols
__global__ __launch_bounds__(256) void k_decode(const unsigned short* __restrict__ zb,
                                                float* __restrict__ out) {
    __shared__ float ls[64 * DSTR];
    const int tid = threadIdx.x;
    const int wave = tid >> 6, lane = tid & 63;
    const int bi = blockIdx.y, bj = blockIdx.x;
    const int lm = lane & 15, lh = lane >> 4;
    const int rA = bi * 64;
    const int cB = bj * 256 + wave * 64;

    short8 a[4][2], b[4][2];
#pragma unroll
    for (int m = 0; m < 4; ++m)
#pragma unroll
        for (int s = 0; s < 2; ++s)
            a[m][s] = *(const short8*)&zb[(size_t)(rA + m * 16 + lm) * LL + s * 32 + lh * 8];
#pragma unroll
    for (int n = 0; n < 4; ++n)
#pragma unroll
        for (int s = 0; s < 2; ++s)
            b[n][s] = *(const short8*)&zb[(size_t)(cB + n * 16 + lm) * LL + s * 32 + lh * 8];

    f32x4 acc[4][4];
#pragma unroll
    for (int m = 0; m < 4; ++m)
#pragma unroll
        for (int n = 0; n < 4; ++n) acc[m][n] = (f32x4){0.f, 0.f, 0.f, 0.f};

#pragma unroll
    for (int m = 0; m < 4; ++m)
#pragma unroll
        for (int n = 0; n < 4; ++n)
#pragma unroll
            for (int s = 0; s < 2; ++s)
                acc[m][n] = __builtin_amdgcn_mfma_f32_16x16x32_bf16(
                    a[m][s], b[n][s], acc[m][n], 0, 0, 0);

    const float SCALE = 1.0f - 2.0f * 1e-7f;
    const float BIAS = 1e-7f * SCALE;
#pragma unroll
    for (int m = 0; m < 4; ++m)
#pragma unroll
        for (int n = 0; n < 4; ++n)
#pragma unroll
            for (int q = 0; q < 4; ++q) {
                float xv = acc[m][n][q];
                float sig = 1.0f / (1.0f + __expf(-xv));
                float val = fmaf(sig, SCALE, BIAS);
                int lr = m * 16 + lh * 4 + q;          // 0..63
                int lc = wave * 64 + n * 16 + lm;      // 0..255
                ls[lr * DSTR + lc] = val;
            }
    __syncthreads();

    // 16 passes; per pass 256 threads write 4 rows x 1KB contiguous
    const int prow = tid >> 6;          // 0..3
    const int pcol = (tid & 63) * 4;    // 0..252
#pragma unroll
    for (int ps = 0; ps < 16; ++ps) {
        int row = ps * 4 + prow;
        f32x4 v = *(const f32x4*)&ls[row * DSTR + pcol];
        __builtin_nontemporal_store(v, (f32x4*)&out[(size_t)(rA + row) * NN + bj * 256 + pcol]);
    }
}

// ---------------- launch ----------------
extern "C" void kernel_launch(void* const* d_in, const int* in_sizes, int n_in,
                              void* d_out, int out_size, void* d_ws, size_t ws_size,
                              hipStream_t stream) {
    const float* x    = (const float*)d_in[0];
    const int*   erow = (const int*)d_in[1];
    const int*   ecol = (const int*)d_in[2];
    const float* ew   = (const float*)d_in[3];
    const float* w1   = (const float*)d_in[4];
    const float* w2   = (const float*)d_in[5];
    float* out = (float*)d_out;

    char* p = (char*)d_ws;
    unsigned short* xb    = (unsigned short*)p; p += (size_t)NN * DD * 2;  // 8 MB
    unsigned short* w1t   = (unsigned short*)p; p += (size_t)HH * DD * 2;  // 256 KB
    unsigned short* w2t   = (unsigned short*)p; p += (size_t)LL * HH * 2;  // 32 KB
    unsigned short* xw1b  = (unsigned short*)p; p += (size_t)NN * HH * 2;  // 4 MB
    unsigned short* haccb = (unsigned short*)p; p += (size_t)NN * HH * 2;  // 4 MB
    unsigned short* hw2b  = (unsigned short*)p; p += (size_t)NN * LL * 2;  // 1 MB
    unsigned short* zb    = (unsigned short*)p; p += (size_t)NN * LL * 2;  // 1 MB
    int*   cnt   = (int*)p;   p += (size_t)NN * 4;        // 32 KB
    int*   slotc = (int*)p;   p += (size_t)NN * CAP * 4;  // 3 MB
    float* slotw = (float*)p; p += (size_t)NN * CAP * 4;  // 3 MB

    k_prep<<<2048, 256, 0, stream>>>(x, w1, w2, xb, w1t, w2t, cnt);
    k_bucket<<<EE / 256, 256, 0, stream>>>(erow, ecol, ew, cnt, slotc, slotw);
    k_gemm1_mfma<<<dim3(2, 128), 256, 0, stream>>>(xb, w1t, xw1b);
    k_spmm1_csr<<<NN / 4, 256, 0, stream>>>(cnt, slotc, slotw, xw1b, haccb);
    k_gemm2_mfma<<<32, 256, 0, stream>>>(haccb, w2t, hw2b);
    k_spmm2_csr<<<NN / 4, 256, 0, stream>>>(cnt, slotc, slotw, hw2b, zb);
    k_decode<<<dim3(32, 128), 256, 0, stream>>>(zb, out);
}